// Round 7
// baseline (393.795 us; speedup 1.0000x reference)
//
#include <hip/hip_runtime.h>
#include <hip/hip_fp16.h>

// SpatialAwareAttention — round 7: dedup'd bf16x3 GEMM ([Ah|Al] x [Wh;Wl],
// virtual K=2304) + double-buffered 2-phase K-loop + XCD-chunked swizzle.
// Attention (MFMA, split-bf16) and fp16 bias-MLP unchanged from round 6.
//
// Pipeline:
//   1) split_hi_lo : x -> A2[4096][1536] bf16 ([Ah|Al])
//   2) split_wT x3 : Wq/Wk/Wv -> W2b[2304 n][1536 k] bf16 ([Wh|Wl] along k)
//   3) mfma_gemm<1>: QKV GEMM (virtual K: AhWh + AhWl + AlWh), dbuf pipeline;
//        epilogue emits split planes Qh/Ql (x0.125), Kh/Kl, Vth/Vtl
//   4) bias_mlp    : bias[b][h][i][j] fp16 (hidden once per pair)
//   5) attn_mfma   : flash attention on MFMA; epilogue writes A2 [Ah|Al]
//   6) split_wT(Wo); mfma_gemm<0>: out = A2 @ Wo^T + bo

typedef unsigned short ushort_t;
typedef unsigned int uint_t;
typedef __attribute__((ext_vector_type(8))) short bf16x8;
typedef __attribute__((ext_vector_type(4))) float f32x4;

__device__ __forceinline__ ushort_t f2b(float f) {  // fp32 -> bf16 (RNE)
    union { float f; uint_t u; } v;
    v.f = f;
    uint_t r = v.u + 0x7fffu + ((v.u >> 16) & 1u);
    return (ushort_t)(r >> 16);
}
__device__ __forceinline__ float b2f(ushort_t b) {
    union { uint_t u; float f; } v;
    v.u = ((uint_t)b) << 16;
    return v.f;
}

__device__ __forceinline__ void gload16(const void* g, void* l) {
    __builtin_amdgcn_global_load_lds(
        (const __attribute__((address_space(1))) unsigned int*)g,
        (__attribute__((address_space(3))) unsigned int*)l, 16, 0, 0);
}

// ---------------------------------------------------------------------------
// X[4096][768] fp32 -> X2[4096][1536] bf16 as [hi | lo]
// ---------------------------------------------------------------------------
__global__ __launch_bounds__(256) void split_hi_lo(const float* __restrict__ X,
                                                   ushort_t* __restrict__ X2) {
    const int idx = blockIdx.x * 256 + threadIdx.x;
    const int m = idx / 192, k4 = (idx - m * 192) * 4;
    float4 v = *(const float4*)&X[(size_t)m * 768 + k4];
    ushort4 hi, lo;
    hi.x = f2b(v.x); lo.x = f2b(v.x - b2f(hi.x));
    hi.y = f2b(v.y); lo.y = f2b(v.y - b2f(hi.y));
    hi.z = f2b(v.z); lo.z = f2b(v.z - b2f(hi.z));
    hi.w = f2b(v.w); lo.w = f2b(v.w - b2f(hi.w));
    ushort_t* row = X2 + (size_t)m * 1536;
    *(ushort4*)&row[k4]       = hi;
    *(ushort4*)&row[768 + k4] = lo;
}

// ---------------------------------------------------------------------------
// W[768 k][768 n] fp32 -> Wt[n_base+n][1536] bf16 as [hi | lo] along k
// ---------------------------------------------------------------------------
__global__ __launch_bounds__(256) void split_wT(const float* __restrict__ W,
                                                ushort_t* __restrict__ Wt,
                                                int n_base) {
    __shared__ float Ws[64][65];
    const int t = threadIdx.x;
    const int rr0 = blockIdx.x * 64, nn0 = blockIdx.y * 64;
    const int c = t & 63, r4 = t >> 6;
#pragma unroll
    for (int e = 0; e < 16; ++e) {
        const int r = r4 + e * 4;
        Ws[r][c] = W[(size_t)(rr0 + r) * 768 + nn0 + c];
    }
    __syncthreads();
#pragma unroll
    for (int e = 0; e < 16; ++e) {
        const int nloc = r4 + e * 4;
        const float v = Ws[c][nloc];
        const ushort_t h = f2b(v);
        const ushort_t l = f2b(v - b2f(h));
        ushort_t* rowp = Wt + (size_t)(n_base + nn0 + nloc) * 1536 + rr0 + c;
        rowp[0]   = h;
        rowp[768] = l;
    }
}

// ---------------------------------------------------------------------------
// GEMM: C[4096 x N] = A @ W (bf16x3 via virtual K=2304 over [Ah|Al],[Wh|Wl]).
// 128x128 tile, BK=64, double-buffered LDS (64KB), 2-phase prefetch pipeline,
// XCD-chunked block swizzle. QKV=1: N=2304 fused epilogue -> split planes.
// ---------------------------------------------------------------------------
__device__ __forceinline__ void kmap(int s, int& ka, int& kb) {
    const int phase = s / 12;           // 0: AhWh  1: AhWl  2: AlWh
    const int q = s - phase * 12;
    ka = ((phase == 2) ? 768 : 0) + q * 64;
    kb = ((phase == 1) ? 768 : 0) + q * 64;
}

template <int QKV>
__global__ __launch_bounds__(256) void mfma_gemm(
    const ushort_t* __restrict__ A2, const ushort_t* __restrict__ Bt,
    const float* __restrict__ bv0, const float* __restrict__ bv1,
    const float* __restrict__ bv2, ushort_t* __restrict__ Qh,
    ushort_t* __restrict__ Ql, ushort_t* __restrict__ Kh,
    ushort_t* __restrict__ Kl, ushort_t* __restrict__ Vth,
    ushort_t* __restrict__ Vtl, float* __restrict__ C0) {
    __shared__ ushort_t As[2][128 * 64];
    __shared__ ushort_t Bs[2][128 * 64];

    const int t = threadIdx.x;
    const int w = t >> 6, lane = t & 63;

    // XCD-chunked bijective swizzle: each XCD gets 4 contiguous m-tiles x all n
    const int nbx = QKV ? 18 : 6;
    const int lid0 = blockIdx.y * nbx + blockIdx.x;
    const int cpx = (nbx * 32) >> 3;
    const int lid = (lid0 & 7) * cpx + (lid0 >> 3);
    const int n0 = (lid % nbx) * 128;
    const int m0 = (lid / nbx) * 128;

    const int wr = (w >> 1) * 64, wc = (w & 1) * 64;

    f32x4 acc[4][4];
#pragma unroll
    for (int i = 0; i < 4; ++i)
#pragma unroll
        for (int j = 0; j < 4; ++j) acc[i][j] = (f32x4){0.f, 0.f, 0.f, 0.f};

    const int srow = t >> 3;
    const int sslot = t & 7;

    auto STAGE = [&](int buf, int ka, int kb) {
#pragma unroll
        for (int it = 0; it < 4; ++it) {
            const int row = srow + it * 32;
            const int sw8 = ((sslot ^ (row & 7)) << 3);
            char* dstA = (char*)&As[buf][0] + it * 4096 + w * 1024;
            char* dstB = (char*)&Bs[buf][0] + it * 4096 + w * 1024;
            gload16(A2 + (size_t)(m0 + row) * 1536 + ka + sw8, dstA);
            gload16(Bt + (size_t)(n0 + row) * 1536 + kb + sw8, dstB);
        }
    };

    auto COMPUTE = [&](int buf) {
#pragma unroll
        for (int kk = 0; kk < 2; ++kk) {
            bf16x8 a[4], b[4];
#pragma unroll
            for (int i = 0; i < 4; ++i) {
                const int ra = wr + i * 16 + (lane & 15);
                const int sa = ((kk << 2) + (lane >> 4)) ^ (ra & 7);
                a[i] = *(const bf16x8*)((const char*)&As[buf][0] + ra * 128 + sa * 16);
                const int rb = wc + i * 16 + (lane & 15);
                const int sb = ((kk << 2) + (lane >> 4)) ^ (rb & 7);
                b[i] = *(const bf16x8*)((const char*)&Bs[buf][0] + rb * 128 + sb * 16);
            }
#pragma unroll
            for (int i = 0; i < 4; ++i)
#pragma unroll
                for (int j = 0; j < 4; ++j)
                    acc[i][j] = __builtin_amdgcn_mfma_f32_16x16x32_bf16(
                        a[i], b[j], acc[i][j], 0, 0, 0);
        }
    };

    int ka, kb;
    kmap(0, ka, kb);
    STAGE(0, ka, kb);
    __syncthreads();
    int cur = 0;
    for (int s = 0; s < 35; ++s) {
        kmap(s + 1, ka, kb);
        STAGE(cur ^ 1, ka, kb);   // next-tile loads fly under this tile's MFMAs
        COMPUTE(cur);
        __syncthreads();          // drains vmcnt -> next buffer ready
        cur ^= 1;
    }
    COMPUTE(cur);

    const int cl = lane & 15, rg = (lane >> 4) * 4;
    if constexpr (QKV) {
        const int which = n0 / 768;
        const int nb = n0 - which * 768 + wc;
        const float* bb = which == 0 ? bv0 : (which == 1 ? bv1 : bv2);
#pragma unroll
        for (int i = 0; i < 4; ++i)
#pragma unroll
            for (int j = 0; j < 4; ++j) {
                const int cw = nb + j * 16 + cl;
                const int h = cw >> 6, d = cw & 63;
                const float badd = bb[cw];
#pragma unroll
                for (int r = 0; r < 4; ++r) {
                    const int gr = m0 + wr + i * 16 + rg + r;
                    const int b = gr >> 10, l = gr & 1023;
                    const int bh = b * 12 + h;
                    float val = acc[i][j][r] + badd;
                    if (which == 0) val *= 0.125f;
                    const ushort_t hi = f2b(val);
                    const ushort_t lo = f2b(val - b2f(hi));
                    if (which == 0) {
                        const size_t idx = ((size_t)((bh << 10) + l)) * 64 + d;
                        Qh[idx] = hi; Ql[idx] = lo;
                    } else if (which == 1) {
                        const size_t idx = ((size_t)((bh << 10) + l)) * 64 + d;
                        Kh[idx] = hi; Kl[idx] = lo;
                    } else {
                        const size_t idx = (((size_t)((bh << 6) + d)) << 10) + l;
                        Vth[idx] = hi; Vtl[idx] = lo;
                    }
                }
            }
    } else {
#pragma unroll
        for (int i = 0; i < 4; ++i)
#pragma unroll
            for (int j = 0; j < 4; ++j) {
                const int gc = n0 + wc + j * 16 + cl;
#pragma unroll
                for (int r = 0; r < 4; ++r) {
                    const int gr = m0 + wr + i * 16 + rg + r;
                    C0[(size_t)gr * 768 + gc] = acc[i][j][r] + bv0[gc];
                }
            }
    }
}

// ---------------------------------------------------------------------------
// bias[b][h][i][j] = relu(delta_ij @ W1 + b1) @ W2[:,h] + b2[h] -> fp16
// ---------------------------------------------------------------------------
__global__ __launch_bounds__(256) void bias_mlp(const float* __restrict__ pos,
                                                const float* __restrict__ W1,
                                                const float* __restrict__ b1,
                                                const float* __restrict__ W2,
                                                const float* __restrict__ b2,
                                                __half* __restrict__ Bias) {
    __shared__ float w1x[32], w1y[32], b1s[32], b2s[12];
    __shared__ float w2T[12][32];

    const int t = threadIdx.x;
    const int i = blockIdx.x;
    const int b = blockIdx.y;

    if (t < 32) { w1x[t] = W1[t]; w1y[t] = W1[32 + t]; b1s[t] = b1[t]; }
    if (t >= 32 && t < 44) b2s[t - 32] = b2[t - 32];
    for (int v = t; v < 384; v += 256) {
        const int u = v / 12, hh = v - u * 12;
        w2T[hh][u] = W2[v];
    }
    __syncthreads();

    const float2 pi2 = *(const float2*)&pos[((b << 10) + i) << 1];
    const float4 pj01 = *(const float4*)&pos[((b << 10) + 2 * t) << 1];
    const float4 pj23 = *(const float4*)&pos[((b << 10) + 2 * t + 512) << 1];
    float dx[4], dy[4];
    dx[0] = pi2.x - pj01.x; dy[0] = pi2.y - pj01.y;
    dx[1] = pi2.x - pj01.z; dy[1] = pi2.y - pj01.w;
    dx[2] = pi2.x - pj23.x; dy[2] = pi2.y - pj23.y;
    dx[3] = pi2.x - pj23.z; dy[3] = pi2.y - pj23.w;

    float acc[4][12];
#pragma unroll
    for (int e = 0; e < 4; ++e)
#pragma unroll
        for (int h = 0; h < 12; ++h) acc[e][h] = b2s[h];

#pragma unroll
    for (int u4 = 0; u4 < 8; ++u4) {
        const float4 ax = *(const float4*)&w1x[u4 << 2];
        const float4 ay = *(const float4*)&w1y[u4 << 2];
        const float4 ab = *(const float4*)&b1s[u4 << 2];
        float4 hv[4];
#pragma unroll
        for (int e = 0; e < 4; ++e) {
            hv[e].x = fmaxf(fmaf(dx[e], ax.x, fmaf(dy[e], ay.x, ab.x)), 0.f);
            hv[e].y = fmaxf(fmaf(dx[e], ax.y, fmaf(dy[e], ay.y, ab.y)), 0.f);
            hv[e].z = fmaxf(fmaf(dx[e], ax.z, fmaf(dy[e], ay.z, ab.z)), 0.f);
            hv[e].w = fmaxf(fmaf(dx[e], ax.w, fmaf(dy[e], ay.w, ab.w)), 0.f);
        }
#pragma unroll
        for (int h = 0; h < 12; ++h) {
            const float4 wv = *(const float4*)&w2T[h][u4 << 2];
#pragma unroll
            for (int e = 0; e < 4; ++e)
                acc[e][h] = fmaf(hv[e].x, wv.x,
                            fmaf(hv[e].y, wv.y,
                            fmaf(hv[e].z, wv.z,
                            fmaf(hv[e].w, wv.w, acc[e][h]))));
        }
    }

    const size_t base = (((size_t)(b * 12)) << 20) + (((size_t)i) << 10);
#pragma unroll
    for (int h = 0; h < 12; ++h) {
        const size_t off = base + (((size_t)h) << 20);
        *(__half2*)&Bias[off + 2 * t]       = __floats2half2_rn(acc[0][h], acc[1][h]);
        *(__half2*)&Bias[off + 2 * t + 512] = __floats2half2_rn(acc[2][h], acc[3][h]);
    }
}

// ---------------------------------------------------------------------------
// MFMA flash attention; bias loaded from precomputed fp16 tensor.
// Grid 768 (XCD-chunk swizzled). 4 waves; wave w: rows [16w,16w+16).
// ---------------------------------------------------------------------------
__global__ __launch_bounds__(256) void attn_mfma(
    const ushort_t* __restrict__ Qh, const ushort_t* __restrict__ Ql,
    const ushort_t* __restrict__ Kh, const ushort_t* __restrict__ Kl,
    const ushort_t* __restrict__ Vth, const ushort_t* __restrict__ Vtl,
    const __half* __restrict__ BiasT, ushort_t* __restrict__ A2) {
    __shared__ ushort_t Kls[2][64][64];    // [plane h/l][j][d]
    __shared__ ushort_t Vls[2][64][64];    // [plane h/l][d][j]
    __shared__ ushort_t P2s[4][2][16][64]; // [wave][plane][row][j] swizzled

    const int t = threadIdx.x;
    const int wgid0 = blockIdx.x;
    const int wgid = (wgid0 & 7) * 96 + (wgid0 >> 3);  // XCD chunk swizzle
    const int bh = wgid >> 4, it = wgid & 15;
    const int b = bh / 12, h = bh - b * 12;
    const int i0 = it << 6;
    const int w = t >> 6, l = t & 63;
    const int l4 = l >> 4, lm = l & 15;

    const __half* bp = BiasT + (((size_t)bh) << 20) +
                       (((size_t)(i0 + 16 * w + l4 * 4)) << 10) + lm;

    const size_t qoff = ((size_t)((bh << 10) + i0 + 16 * w + lm)) * 64 + l4 * 8;
    const bf16x8 qh0 = *(const bf16x8*)(Qh + qoff);
    const bf16x8 qh1 = *(const bf16x8*)(Qh + qoff + 32);
    const bf16x8 ql0 = *(const bf16x8*)(Ql + qoff);
    const bf16x8 ql1 = *(const bf16x8*)(Ql + qoff + 32);

    float m_[4], l_[4];
    f32x4 o_[4];
#pragma unroll
    for (int r = 0; r < 4; ++r) { m_[r] = -1e30f; l_[r] = 0.f; }
#pragma unroll
    for (int db = 0; db < 4; ++db) o_[db] = (f32x4){0.f, 0.f, 0.f, 0.f};

    for (int jt = 0; jt < 16; ++jt) {
        const int j0 = jt << 6;

        float bias_r[4][4];
#pragma unroll
        for (int cb = 0; cb < 4; ++cb)
#pragma unroll
            for (int r = 0; r < 4; ++r)
                bias_r[cb][r] = __half2float(bp[(r << 10) + j0 + 16 * cb]);

        __syncthreads();
        {   // wave w stages one 8KB plane: 0=Kh 1=Kl 2=Vth 3=Vtl
            ushort_t* lb = (w == 0) ? &Kls[0][0][0]
                         : (w == 1) ? &Kls[1][0][0]
                         : (w == 2) ? &Vls[0][0][0] : &Vls[1][0][0];
            const ushort_t* gt = (w == 0) ? Kh : (w == 1) ? Kl
                               : (w == 2) ? Vth : Vtl;
#pragma unroll
            for (int ch = 0; ch < 8; ++ch) {
                const int row = ch * 8 + (l >> 3);
                const int off8 = (((l & 7) ^ (row & 7)) << 3);
                const ushort_t* src =
                    (w < 2) ? gt + ((size_t)((bh << 10) + j0 + row)) * 64 + off8
                            : gt + ((size_t)((bh << 6) + row)) * 1024 + j0 + off8;
                gload16(src, (char*)lb + ch * 1024);
            }
        }
        __syncthreads();

        // ---- S = Q.K^T (QhKh + QhKl + QlKh) ----
        f32x4 s_[4];
#pragma unroll
        for (int cb = 0; cb < 4; ++cb) {
            const int row = 16 * cb + lm;
            const int sw = row & 7;
            const char* k0p = (const char*)&Kls[0][0][0] + row * 128;
            const char* k1p = (const char*)&Kls[1][0][0] + row * 128;
            const bf16x8 kh0 = *(const bf16x8*)(k0p + ((l4 + 0) ^ sw) * 16);
            const bf16x8 kh1 = *(const bf16x8*)(k0p + ((l4 + 4) ^ sw) * 16);
            const bf16x8 kl0 = *(const bf16x8*)(k1p + ((l4 + 0) ^ sw) * 16);
            const bf16x8 kl1 = *(const bf16x8*)(k1p + ((l4 + 4) ^ sw) * 16);
            f32x4 a = (f32x4){0.f, 0.f, 0.f, 0.f};
            a = __builtin_amdgcn_mfma_f32_16x16x32_bf16(qh0, kh0, a, 0, 0, 0);
            a = __builtin_amdgcn_mfma_f32_16x16x32_bf16(qh1, kh1, a, 0, 0, 0);
            a = __builtin_amdgcn_mfma_f32_16x16x32_bf16(qh0, kl0, a, 0, 0, 0);
            a = __builtin_amdgcn_mfma_f32_16x16x32_bf16(qh1, kl1, a, 0, 0, 0);
            a = __builtin_amdgcn_mfma_f32_16x16x32_bf16(ql0, kh0, a, 0, 0, 0);
            a = __builtin_amdgcn_mfma_f32_16x16x32_bf16(ql1, kh1, a, 0, 0, 0);
            s_[cb] = a;
        }

#pragma unroll
        for (int cb = 0; cb < 4; ++cb)
#pragma unroll
            for (int r = 0; r < 4; ++r) s_[cb][r] += bias_r[cb][r];

        // ---- online softmax ----
        float corr[4];
#pragma unroll
        for (int r = 0; r < 4; ++r) {
            float mx = fmaxf(fmaxf(s_[0][r], s_[1][r]), fmaxf(s_[2][r], s_[3][r]));
            mx = fmaxf(mx, __shfl_xor(mx, 1));
            mx = fmaxf(mx, __shfl_xor(mx, 2));
            mx = fmaxf(mx, __shfl_xor(mx, 4));
            mx = fmaxf(mx, __shfl_xor(mx, 8));
            const float mn = fmaxf(m_[r], mx);
            corr[r] = __expf(m_[r] - mn);
            m_[r] = mn;
            float ps = 0.f;
#pragma unroll
            for (int cb = 0; cb < 4; ++cb) {
                s_[cb][r] = __expf(s_[cb][r] - mn);
                ps += s_[cb][r];
            }
            ps += __shfl_xor(ps, 1);
            ps += __shfl_xor(ps, 2);
            ps += __shfl_xor(ps, 4);
            ps += __shfl_xor(ps, 8);
            l_[r] = fmaf(l_[r], corr[r], ps);
            o_[0][r] *= corr[r]; o_[1][r] *= corr[r];
            o_[2][r] *= corr[r]; o_[3][r] *= corr[r];
        }

        // ---- split P -> wave-private swizzled LDS ----
        char* pw = (char*)&P2s[w][0][0][0];
#pragma unroll
        for (int cb = 0; cb < 4; ++cb)
#pragma unroll
            for (int r = 0; r < 4; ++r) {
                const float p = s_[cb][r];
                const ushort_t ph = f2b(p);
                const ushort_t pl = f2b(p - b2f(ph));
                const int rl = l4 * 4 + r;
                const int bo = rl * 128 + ((((lm >> 3) + 2 * cb) ^ (rl & 7)) << 4)
                               + ((2 * lm) & 15);
                *(ushort_t*)(pw + bo) = ph;
                *(ushort_t*)(pw + 2048 + bo) = pl;
            }

        const int psw = lm & 7;
        const char* pb = (const char*)&P2s[w][0][0][0] + lm * 128;
        const bf16x8 pa0 = *(const bf16x8*)(pb + ((l4 + 0) ^ psw) * 16);
        const bf16x8 pa1 = *(const bf16x8*)(pb + ((l4 + 4) ^ psw) * 16);
        const bf16x8 pb0 = *(const bf16x8*)(pb + 2048 + ((l4 + 0) ^ psw) * 16);
        const bf16x8 pb1 = *(const bf16x8*)(pb + 2048 + ((l4 + 4) ^ psw) * 16);

        // ---- O += P.V (PhVh + PhVl + PlVh) ----
#pragma unroll
        for (int db = 0; db < 4; ++db) {
            const int vrow = 16 * db + lm;
            const int vw = vrow & 7;
            const char* v0p = (const char*)&Vls[0][0][0] + vrow * 128;
            const char* v1p = (const char*)&Vls[1][0][0] + vrow * 128;
            const bf16x8 vh0 = *(const bf16x8*)(v0p + ((l4 + 0) ^ vw) * 16);
            const bf16x8 vh1 = *(const bf16x8*)(v0p + ((l4 + 4) ^ vw) * 16);
            const bf16x8 vl0 = *(const bf16x8*)(v1p + ((l4 + 0) ^ vw) * 16);
            const bf16x8 vl1 = *(const bf16x8*)(v1p + ((l4 + 4) ^ vw) * 16);
            f32x4 a = o_[db];
            a = __builtin_amdgcn_mfma_f32_16x16x32_bf16(pa0, vh0, a, 0, 0, 0);
            a = __builtin_amdgcn_mfma_f32_16x16x32_bf16(pa1, vh1, a, 0, 0, 0);
            a = __builtin_amdgcn_mfma_f32_16x16x32_bf16(pa0, vl0, a, 0, 0, 0);
            a = __builtin_amdgcn_mfma_f32_16x16x32_bf16(pa1, vl1, a, 0, 0, 0);
            a = __builtin_amdgcn_mfma_f32_16x16x32_bf16(pb0, vh0, a, 0, 0, 0);
            a = __builtin_amdgcn_mfma_f32_16x16x32_bf16(pb1, vh1, a, 0, 0, 0);
            o_[db] = a;
        }
    }

    // ---- epilogue: normalize, split, write A2 [Ah|Al] ----
    const int mrow = (b << 10) + i0 + 16 * w + l4 * 4;
#pragma unroll
    for (int r = 0; r < 4; ++r) {
        const float inv = 1.f / l_[r];
        ushort_t* rowp = A2 + (size_t)(mrow + r) * 1536;
#pragma unroll
        for (int db = 0; db < 4; ++db) {
            const float val = o_[db][r] * inv;
            const ushort_t hi = f2b(val);
            const ushort_t lo = f2b(val - b2f(hi));
            const int c = (h << 6) + 16 * db + lm;
            rowp[c] = hi;
            rowp[768 + c] = lo;
        }
    }
}

extern "C" void kernel_launch(void* const* d_in, const int* in_sizes, int n_in,
                              void* d_out, int out_size, void* d_ws, size_t ws_size,
                              hipStream_t stream) {
    const float* x   = (const float*)d_in[0];
    const float* pos = (const float*)d_in[1];
    const float* Wq  = (const float*)d_in[2];
    const float* bq  = (const float*)d_in[3];
    const float* Wk  = (const float*)d_in[4];
    const float* bk  = (const float*)d_in[5];
    const float* Wv  = (const float*)d_in[6];
    const float* bv  = (const float*)d_in[7];
    const float* Wo  = (const float*)d_in[8];
    const float* bo  = (const float*)d_in[9];
    const float* W1  = (const float*)d_in[10];
    const float* b1  = (const float*)d_in[11];
    const float* W2  = (const float*)d_in[12];
    const float* b2  = (const float*)d_in[13];
    float* out = (float*)d_out;

    // ws: 6 split planes (6 x 6.29MB) | A2 12.6MB | W2b 7.1MB | BiasH 100.7MB
    ushort_t* Qhb = (ushort_t*)d_ws;          // [48][1024][64]
    ushort_t* Qlb = Qhb + 3145728;
    ushort_t* Khb = Qlb + 3145728;
    ushort_t* Klb = Khb + 3145728;
    ushort_t* Vth = Klb + 3145728;            // [48][64][1024]
    ushort_t* Vtl = Vth + 3145728;
    ushort_t* A2  = Vtl + 3145728;            // [4096][1536]
    ushort_t* W2b = A2 + 6291456;             // [2304][1536]
    __half* BiasH = (__half*)(W2b + 3538944); // [48][1024][1024]

    split_hi_lo<<<3072, 256, 0, stream>>>(x, A2);
    split_wT<<<dim3(12, 12), 256, 0, stream>>>(Wq, W2b, 0);
    split_wT<<<dim3(12, 12), 256, 0, stream>>>(Wk, W2b, 768);
    split_wT<<<dim3(12, 12), 256, 0, stream>>>(Wv, W2b, 1536);

    mfma_gemm<1><<<dim3(18, 32), 256, 0, stream>>>(
        A2, W2b, bq, bk, bv, Qhb, Qlb, Khb, Klb, Vth, Vtl, nullptr);

    bias_mlp<<<dim3(1024, 4), 256, 0, stream>>>(pos, W1, b1, W2, b2, BiasH);

    attn_mfma<<<768, 256, 0, stream>>>(Qhb, Qlb, Khb, Klb, Vth, Vtl, BiasH, A2);

    split_wT<<<dim3(12, 12), 256, 0, stream>>>(Wo, W2b, 0);
    mfma_gemm<0><<<dim3(6, 32), 256, 0, stream>>>(
        A2, W2b, bo, nullptr, nullptr, nullptr, nullptr, nullptr, nullptr, nullptr,
        nullptr, out);
}

// Round 8
// 335.045 us; speedup vs baseline: 1.1753x; 1.1753x over previous
//
#include <hip/hip_runtime.h>
#include <hip/hip_fp16.h>

// SpatialAwareAttention — round 8: 4-plane co-staged bf16x3 GEMM.
// Stage {Ah,Al,Wh,Wl} (BK=32, 32KB single-buffer) once per k-chunk; run all
// three product terms (AhWh+AhWl+AlWh) from it -> 48 MFMA per barrier pair,
// 24 steps (was 36 steps x 32 MFMA). bias_mlp split 2-way for latency.
// Attention (MFMA split-bf16 + fp16 bias) unchanged from round 7.

typedef unsigned short ushort_t;
typedef unsigned int uint_t;
typedef __attribute__((ext_vector_type(8))) short bf16x8;
typedef __attribute__((ext_vector_type(4))) float f32x4;

__device__ __forceinline__ ushort_t f2b(float f) {  // fp32 -> bf16 (RNE)
    union { float f; uint_t u; } v;
    v.f = f;
    uint_t r = v.u + 0x7fffu + ((v.u >> 16) & 1u);
    return (ushort_t)(r >> 16);
}
__device__ __forceinline__ float b2f(ushort_t b) {
    union { uint_t u; float f; } v;
    v.u = ((uint_t)b) << 16;
    return v.f;
}

__device__ __forceinline__ void gload16(const void* g, void* l) {
    __builtin_amdgcn_global_load_lds(
        (const __attribute__((address_space(1))) unsigned int*)g,
        (__attribute__((address_space(3))) unsigned int*)l, 16, 0, 0);
}

// ---------------------------------------------------------------------------
// X[4096][768] fp32 -> X2[4096][1536] bf16 as [hi | lo]
// ---------------------------------------------------------------------------
__global__ __launch_bounds__(256) void split_hi_lo(const float* __restrict__ X,
                                                   ushort_t* __restrict__ X2) {
    const int idx = blockIdx.x * 256 + threadIdx.x;
    const int m = idx / 192, k4 = (idx - m * 192) * 4;
    float4 v = *(const float4*)&X[(size_t)m * 768 + k4];
    ushort4 hi, lo;
    hi.x = f2b(v.x); lo.x = f2b(v.x - b2f(hi.x));
    hi.y = f2b(v.y); lo.y = f2b(v.y - b2f(hi.y));
    hi.z = f2b(v.z); lo.z = f2b(v.z - b2f(hi.z));
    hi.w = f2b(v.w); lo.w = f2b(v.w - b2f(hi.w));
    ushort_t* row = X2 + (size_t)m * 1536;
    *(ushort4*)&row[k4]       = hi;
    *(ushort4*)&row[768 + k4] = lo;
}

// ---------------------------------------------------------------------------
// W[768 k][768 n] fp32 -> Wt[n_base+n][1536] bf16 as [hi | lo] along k
// ---------------------------------------------------------------------------
__global__ __launch_bounds__(256) void split_wT(const float* __restrict__ W,
                                                ushort_t* __restrict__ Wt,
                                                int n_base) {
    __shared__ float Ws[64][65];
    const int t = threadIdx.x;
    const int rr0 = blockIdx.x * 64, nn0 = blockIdx.y * 64;
    const int c = t & 63, r4 = t >> 6;
#pragma unroll
    for (int e = 0; e < 16; ++e) {
        const int r = r4 + e * 4;
        Ws[r][c] = W[(size_t)(rr0 + r) * 768 + nn0 + c];
    }
    __syncthreads();
#pragma unroll
    for (int e = 0; e < 16; ++e) {
        const int nloc = r4 + e * 4;
        const float v = Ws[c][nloc];
        const ushort_t h = f2b(v);
        const ushort_t l = f2b(v - b2f(h));
        ushort_t* rowp = Wt + (size_t)(n_base + nn0 + nloc) * 1536 + rr0 + c;
        rowp[0]   = h;
        rowp[768] = l;
    }
}

// ---------------------------------------------------------------------------
// GEMM: C[4096 x N] = A @ W  (bf16x3: AhWh + AhWl + AlWh).
// 128x128 tile, BK=32, 4 co-staged planes {Ah,Al,Wh,Wl} = 32KB single-buffer,
// 24 steps x 48 MFMA/wave. XCD-chunked block swizzle.
// Swizzle: 64B rows, 4 slots of 16B; slot ^= (row>>1)&3 (both sides).
// ---------------------------------------------------------------------------
template <int QKV>
__global__ __launch_bounds__(256) void mfma_gemm(
    const ushort_t* __restrict__ A2, const ushort_t* __restrict__ Bt,
    const float* __restrict__ bv0, const float* __restrict__ bv1,
    const float* __restrict__ bv2, ushort_t* __restrict__ Qh,
    ushort_t* __restrict__ Ql, ushort_t* __restrict__ Kh,
    ushort_t* __restrict__ Kl, ushort_t* __restrict__ Vth,
    ushort_t* __restrict__ Vtl, float* __restrict__ C0) {
    __shared__ ushort_t Ls[4][128 * 32];   // 0=Ah 1=Al 2=Wh 3=Wl  (8KB each)

    const int t = threadIdx.x;
    const int w = t >> 6, lane = t & 63;
    const int lm = lane & 15, l4 = lane >> 4;

    // XCD-chunked bijective swizzle (grid%8==0 in both uses)
    const int nbx = QKV ? 18 : 6;
    const int lid0 = blockIdx.y * nbx + blockIdx.x;
    const int cpx = (nbx * 32) >> 3;
    const int lid = (lid0 & 7) * cpx + (lid0 >> 3);
    const int n0 = (lid % nbx) * 128;
    const int m0 = (lid / nbx) * 128;

    const int wr = (w >> 1) * 64, wc = (w & 1) * 64;

    f32x4 acc[4][4];
#pragma unroll
    for (int i = 0; i < 4; ++i)
#pragma unroll
        for (int j = 0; j < 4; ++j) acc[i][j] = (f32x4){0.f, 0.f, 0.f, 0.f};

    // staging geometry: i2 = t + 256e (512 slots/plane); row=i2>>2, slot=i2&3
    const int sr0 = t >> 2, ss0 = t & 3;
    const int sr1 = (t + 256) >> 2, ss1 = (t + 256) & 3;
    const int k80 = (ss0 ^ ((sr0 >> 1) & 3)) << 3;   // pre-swizzled src k-chunk
    const int k81 = (ss1 ^ ((sr1 >> 1) & 3)) << 3;

    const ushort_t* baseA = A2 + (size_t)m0 * 1536;
    const ushort_t* baseB = Bt + (size_t)n0 * 1536;

    for (int q = 0; q < 24; ++q) {
        const int k0 = q * 32;
        __syncthreads();   // prior step's ds_reads complete before overwrite
        {
            // plane 0: Ah, 1: Al, 2: Wh, 3: Wl
            gload16(baseA + (size_t)sr0 * 1536 + k0 + k80,
                    (char*)&Ls[0][0] + t * 16);
            gload16(baseA + (size_t)sr1 * 1536 + k0 + k81,
                    (char*)&Ls[0][0] + (t + 256) * 16);
            gload16(baseA + (size_t)sr0 * 1536 + 768 + k0 + k80,
                    (char*)&Ls[1][0] + t * 16);
            gload16(baseA + (size_t)sr1 * 1536 + 768 + k0 + k81,
                    (char*)&Ls[1][0] + (t + 256) * 16);
            gload16(baseB + (size_t)sr0 * 1536 + k0 + k80,
                    (char*)&Ls[2][0] + t * 16);
            gload16(baseB + (size_t)sr1 * 1536 + k0 + k81,
                    (char*)&Ls[2][0] + (t + 256) * 16);
            gload16(baseB + (size_t)sr0 * 1536 + 768 + k0 + k80,
                    (char*)&Ls[3][0] + t * 16);
            gload16(baseB + (size_t)sr1 * 1536 + 768 + k0 + k81,
                    (char*)&Ls[3][0] + (t + 256) * 16);
        }
        __syncthreads();   // staged data visible (vmcnt drained by barrier)

        bf16x8 ah[4], al[4];
#pragma unroll
        for (int i = 0; i < 4; ++i) {
            const int ra = wr + i * 16 + lm;
            const int sa = (l4 ^ ((ra >> 1) & 3)) << 4;
            ah[i] = *(const bf16x8*)((const char*)&Ls[0][0] + ra * 64 + sa);
            al[i] = *(const bf16x8*)((const char*)&Ls[1][0] + ra * 64 + sa);
        }
#pragma unroll
        for (int j = 0; j < 4; ++j) {
            const int rb = wc + j * 16 + lm;
            const int sb = (l4 ^ ((rb >> 1) & 3)) << 4;
            const bf16x8 bh = *(const bf16x8*)((const char*)&Ls[2][0] + rb * 64 + sb);
            const bf16x8 bl = *(const bf16x8*)((const char*)&Ls[3][0] + rb * 64 + sb);
#pragma unroll
            for (int i = 0; i < 4; ++i) {
                acc[i][j] = __builtin_amdgcn_mfma_f32_16x16x32_bf16(ah[i], bh,
                                                                    acc[i][j], 0, 0, 0);
                acc[i][j] = __builtin_amdgcn_mfma_f32_16x16x32_bf16(ah[i], bl,
                                                                    acc[i][j], 0, 0, 0);
                acc[i][j] = __builtin_amdgcn_mfma_f32_16x16x32_bf16(al[i], bh,
                                                                    acc[i][j], 0, 0, 0);
            }
        }
    }

    const int cl = lane & 15, rg = (lane >> 4) * 4;
    if constexpr (QKV) {
        const int which = n0 / 768;
        const int nb = n0 - which * 768 + wc;
        const float* bb = which == 0 ? bv0 : (which == 1 ? bv1 : bv2);
#pragma unroll
        for (int i = 0; i < 4; ++i)
#pragma unroll
            for (int j = 0; j < 4; ++j) {
                const int cw = nb + j * 16 + cl;
                const int h = cw >> 6, d = cw & 63;
                const float badd = bb[cw];
#pragma unroll
                for (int r = 0; r < 4; ++r) {
                    const int gr = m0 + wr + i * 16 + rg + r;
                    const int b = gr >> 10, l = gr & 1023;
                    const int bh2 = b * 12 + h;
                    float val = acc[i][j][r] + badd;
                    if (which == 0) val *= 0.125f;
                    const ushort_t hi = f2b(val);
                    const ushort_t lo = f2b(val - b2f(hi));
                    if (which == 0) {
                        const size_t idx = ((size_t)((bh2 << 10) + l)) * 64 + d;
                        Qh[idx] = hi; Ql[idx] = lo;
                    } else if (which == 1) {
                        const size_t idx = ((size_t)((bh2 << 10) + l)) * 64 + d;
                        Kh[idx] = hi; Kl[idx] = lo;
                    } else {
                        const size_t idx = (((size_t)((bh2 << 6) + d)) << 10) + l;
                        Vth[idx] = hi; Vtl[idx] = lo;
                    }
                }
            }
    } else {
#pragma unroll
        for (int i = 0; i < 4; ++i)
#pragma unroll
            for (int j = 0; j < 4; ++j) {
                const int gc = n0 + wc + j * 16 + cl;
#pragma unroll
                for (int r = 0; r < 4; ++r) {
                    const int gr = m0 + wr + i * 16 + rg + r;
                    C0[(size_t)gr * 768 + gc] = acc[i][j][r] + bv0[gc];
                }
            }
    }
}

// ---------------------------------------------------------------------------
// bias[b][h][i][j] = relu(delta_ij @ W1 + b1) @ W2[:,h] + b2[h] -> fp16
// Grid (1024 i, 4 b, 2 jz): thread handles j = jz*512 + {2t, 2t+1}.
// ---------------------------------------------------------------------------
__global__ __launch_bounds__(256) void bias_mlp(const float* __restrict__ pos,
                                                const float* __restrict__ W1,
                                                const float* __restrict__ b1,
                                                const float* __restrict__ W2,
                                                const float* __restrict__ b2,
                                                __half* __restrict__ Bias) {
    __shared__ float w1x[32], w1y[32], b1s[32], b2s[12];
    __shared__ float w2T[12][32];

    const int t = threadIdx.x;
    const int i = blockIdx.x;
    const int b = blockIdx.y;
    const int j0 = blockIdx.z * 512;

    if (t < 32) { w1x[t] = W1[t]; w1y[t] = W1[32 + t]; b1s[t] = b1[t]; }
    if (t >= 32 && t < 44) b2s[t - 32] = b2[t - 32];
    for (int v = t; v < 384; v += 256) {
        const int u = v / 12, hh = v - u * 12;
        w2T[hh][u] = W2[v];
    }
    __syncthreads();

    const float2 pi2 = *(const float2*)&pos[((b << 10) + i) << 1];
    const float4 pj01 = *(const float4*)&pos[((b << 10) + j0 + 2 * t) << 1];
    float dx[2], dy[2];
    dx[0] = pi2.x - pj01.x; dy[0] = pi2.y - pj01.y;
    dx[1] = pi2.x - pj01.z; dy[1] = pi2.y - pj01.w;

    float acc[2][12];
#pragma unroll
    for (int e = 0; e < 2; ++e)
#pragma unroll
        for (int h = 0; h < 12; ++h) acc[e][h] = b2s[h];

#pragma unroll
    for (int u4 = 0; u4 < 8; ++u4) {
        const float4 ax = *(const float4*)&w1x[u4 << 2];
        const float4 ay = *(const float4*)&w1y[u4 << 2];
        const float4 ab = *(const float4*)&b1s[u4 << 2];
        float4 hv[2];
#pragma unroll
        for (int e = 0; e < 2; ++e) {
            hv[e].x = fmaxf(fmaf(dx[e], ax.x, fmaf(dy[e], ay.x, ab.x)), 0.f);
            hv[e].y = fmaxf(fmaf(dx[e], ax.y, fmaf(dy[e], ay.y, ab.y)), 0.f);
            hv[e].z = fmaxf(fmaf(dx[e], ax.z, fmaf(dy[e], ay.z, ab.z)), 0.f);
            hv[e].w = fmaxf(fmaf(dx[e], ax.w, fmaf(dy[e], ay.w, ab.w)), 0.f);
        }
#pragma unroll
        for (int h = 0; h < 12; ++h) {
            const float4 wv = *(const float4*)&w2T[h][u4 << 2];
#pragma unroll
            for (int e = 0; e < 2; ++e)
                acc[e][h] = fmaf(hv[e].x, wv.x,
                            fmaf(hv[e].y, wv.y,
                            fmaf(hv[e].z, wv.z,
                            fmaf(hv[e].w, wv.w, acc[e][h]))));
        }
    }

    const size_t base = (((size_t)(b * 12)) << 20) + (((size_t)i) << 10) + j0;
#pragma unroll
    for (int h = 0; h < 12; ++h)
        *(__half2*)&Bias[base + (((size_t)h) << 20) + 2 * t] =
            __floats2half2_rn(acc[0][h], acc[1][h]);
}

// ---------------------------------------------------------------------------
// MFMA flash attention; bias loaded from precomputed fp16 tensor.
// Grid 768 (XCD-chunk swizzled). 4 waves; wave w: rows [16w,16w+16).
// ---------------------------------------------------------------------------
__global__ __launch_bounds__(256) void attn_mfma(
    const ushort_t* __restrict__ Qh, const ushort_t* __restrict__ Ql,
    const ushort_t* __restrict__ Kh, const ushort_t* __restrict__ Kl,
    const ushort_t* __restrict__ Vth, const ushort_t* __restrict__ Vtl,
    const __half* __restrict__ BiasT, ushort_t* __restrict__ A2) {
    __shared__ ushort_t Kls[2][64][64];    // [plane h/l][j][d]
    __shared__ ushort_t Vls[2][64][64];    // [plane h/l][d][j]
    __shared__ ushort_t P2s[4][2][16][64]; // [wave][plane][row][j] swizzled

    const int t = threadIdx.x;
    const int wgid0 = blockIdx.x;
    const int wgid = (wgid0 & 7) * 96 + (wgid0 >> 3);  // XCD chunk swizzle
    const int bh = wgid >> 4, it = wgid & 15;
    const int b = bh / 12, h = bh - b * 12;
    const int i0 = it << 6;
    const int w = t >> 6, l = t & 63;
    const int l4 = l >> 4, lm = l & 15;

    const __half* bp = BiasT + (((size_t)bh) << 20) +
                       (((size_t)(i0 + 16 * w + l4 * 4)) << 10) + lm;

    const size_t qoff = ((size_t)((bh << 10) + i0 + 16 * w + lm)) * 64 + l4 * 8;
    const bf16x8 qh0 = *(const bf16x8*)(Qh + qoff);
    const bf16x8 qh1 = *(const bf16x8*)(Qh + qoff + 32);
    const bf16x8 ql0 = *(const bf16x8*)(Ql + qoff);
    const bf16x8 ql1 = *(const bf16x8*)(Ql + qoff + 32);

    float m_[4], l_[4];
    f32x4 o_[4];
#pragma unroll
    for (int r = 0; r < 4; ++r) { m_[r] = -1e30f; l_[r] = 0.f; }
#pragma unroll
    for (int db = 0; db < 4; ++db) o_[db] = (f32x4){0.f, 0.f, 0.f, 0.f};

    for (int jt = 0; jt < 16; ++jt) {
        const int j0 = jt << 6;

        float bias_r[4][4];
#pragma unroll
        for (int cb = 0; cb < 4; ++cb)
#pragma unroll
            for (int r = 0; r < 4; ++r)
                bias_r[cb][r] = __half2float(bp[(r << 10) + j0 + 16 * cb]);

        __syncthreads();
        {   // wave w stages one 8KB plane: 0=Kh 1=Kl 2=Vth 3=Vtl
            ushort_t* lb = (w == 0) ? &Kls[0][0][0]
                         : (w == 1) ? &Kls[1][0][0]
                         : (w == 2) ? &Vls[0][0][0] : &Vls[1][0][0];
            const ushort_t* gt = (w == 0) ? Kh : (w == 1) ? Kl
                               : (w == 2) ? Vth : Vtl;
#pragma unroll
            for (int ch = 0; ch < 8; ++ch) {
                const int row = ch * 8 + (l >> 3);
                const int off8 = (((l & 7) ^ (row & 7)) << 3);
                const ushort_t* src =
                    (w < 2) ? gt + ((size_t)((bh << 10) + j0 + row)) * 64 + off8
                            : gt + ((size_t)((bh << 6) + row)) * 1024 + j0 + off8;
                gload16(src, (char*)lb + ch * 1024);
            }
        }
        __syncthreads();

        // ---- S = Q.K^T (QhKh + QhKl + QlKh) ----
        f32x4 s_[4];
#pragma unroll
        for (int cb = 0; cb < 4; ++cb) {
            const int row = 16 * cb + lm;
            const int sw = row & 7;
            const char* k0p = (const char*)&Kls[0][0][0] + row * 128;
            const char* k1p = (const char*)&Kls[1][0][0] + row * 128;
            const bf16x8 kh0 = *(const bf16x8*)(k0p + ((l4 + 0) ^ sw) * 16);
            const bf16x8 kh1 = *(const bf16x8*)(k0p + ((l4 + 4) ^ sw) * 16);
            const bf16x8 kl0 = *(const bf16x8*)(k1p + ((l4 + 0) ^ sw) * 16);
            const bf16x8 kl1 = *(const bf16x8*)(k1p + ((l4 + 4) ^ sw) * 16);
            f32x4 a = (f32x4){0.f, 0.f, 0.f, 0.f};
            a = __builtin_amdgcn_mfma_f32_16x16x32_bf16(qh0, kh0, a, 0, 0, 0);
            a = __builtin_amdgcn_mfma_f32_16x16x32_bf16(qh1, kh1, a, 0, 0, 0);
            a = __builtin_amdgcn_mfma_f32_16x16x32_bf16(qh0, kl0, a, 0, 0, 0);
            a = __builtin_amdgcn_mfma_f32_16x16x32_bf16(qh1, kl1, a, 0, 0, 0);
            a = __builtin_amdgcn_mfma_f32_16x16x32_bf16(ql0, kh0, a, 0, 0, 0);
            a = __builtin_amdgcn_mfma_f32_16x16x32_bf16(ql1, kh1, a, 0, 0, 0);
            s_[cb] = a;
        }

#pragma unroll
        for (int cb = 0; cb < 4; ++cb)
#pragma unroll
            for (int r = 0; r < 4; ++r) s_[cb][r] += bias_r[cb][r];

        // ---- online softmax ----
        float corr[4];
#pragma unroll
        for (int r = 0; r < 4; ++r) {
            float mx = fmaxf(fmaxf(s_[0][r], s_[1][r]), fmaxf(s_[2][r], s_[3][r]));
            mx = fmaxf(mx, __shfl_xor(mx, 1));
            mx = fmaxf(mx, __shfl_xor(mx, 2));
            mx = fmaxf(mx, __shfl_xor(mx, 4));
            mx = fmaxf(mx, __shfl_xor(mx, 8));
            const float mn = fmaxf(m_[r], mx);
            corr[r] = __expf(m_[r] - mn);
            m_[r] = mn;
            float ps = 0.f;
#pragma unroll
            for (int cb = 0; cb < 4; ++cb) {
                s_[cb][r] = __expf(s_[cb][r] - mn);
                ps += s_[cb][r];
            }
            ps += __shfl_xor(ps, 1);
            ps += __shfl_xor(ps, 2);
            ps += __shfl_xor(ps, 4);
            ps += __shfl_xor(ps, 8);
            l_[r] = fmaf(l_[r], corr[r], ps);
            o_[0][r] *= corr[r]; o_[1][r] *= corr[r];
            o_[2][r] *= corr[r]; o_[3][r] *= corr[r];
        }

        // ---- split P -> wave-private swizzled LDS ----
        char* pw = (char*)&P2s[w][0][0][0];
#pragma unroll
        for (int cb = 0; cb < 4; ++cb)
#pragma unroll
            for (int r = 0; r < 4; ++r) {
                const float p = s_[cb][r];
                const ushort_t ph = f2b(p);
                const ushort_t pl = f2b(p - b2f(ph));
                const int rl = l4 * 4 + r;
                const int bo = rl * 128 + ((((lm >> 3) + 2 * cb) ^ (rl & 7)) << 4)
                               + ((2 * lm) & 15);
                *(ushort_t*)(pw + bo) = ph;
                *(ushort_t*)(pw + 2048 + bo) = pl;
            }

        const int psw = lm & 7;
        const char* pb = (const char*)&P2s[w][0][0][0] + lm * 128;
        const bf16x8 pa0 = *(const bf16x8*)(pb + ((l4 + 0) ^ psw) * 16);
        const bf16x8 pa1 = *(const bf16x8*)(pb + ((l4 + 4) ^ psw) * 16);
        const bf16x8 pb0 = *(const bf16x8*)(pb + 2048 + ((l4 + 0) ^ psw) * 16);
        const bf16x8 pb1 = *(const bf16x8*)(pb + 2048 + ((l4 + 4) ^ psw) * 16);

        // ---- O += P.V (PhVh + PhVl + PlVh) ----
#pragma unroll
        for (int db = 0; db < 4; ++db) {
            const int vrow = 16 * db + lm;
            const int vw = vrow & 7;
            const char* v0p = (const char*)&Vls[0][0][0] + vrow * 128;
            const char* v1p = (const char*)&Vls[1][0][0] + vrow * 128;
            const bf16x8 vh0 = *(const bf16x8*)(v0p + ((l4 + 0) ^ vw) * 16);
            const bf16x8 vh1 = *(const bf16x8*)(v0p + ((l4 + 4) ^ vw) * 16);
            const bf16x8 vl0 = *(const bf16x8*)(v1p + ((l4 + 0) ^ vw) * 16);
            const bf16x8 vl1 = *(const bf16x8*)(v1p + ((l4 + 4) ^ vw) * 16);
            f32x4 a = o_[db];
            a = __builtin_amdgcn_mfma_f32_16x16x32_bf16(pa0, vh0, a, 0, 0, 0);
            a = __builtin_amdgcn_mfma_f32_16x16x32_bf16(pa1, vh1, a, 0, 0, 0);
            a = __builtin_amdgcn_mfma_f32_16x16x32_bf16(pa0, vl0, a, 0, 0, 0);
            a = __builtin_amdgcn_mfma_f32_16x16x32_bf16(pa1, vl1, a, 0, 0, 0);
            a = __builtin_amdgcn_mfma_f32_16x16x32_bf16(pb0, vh0, a, 0, 0, 0);
            a = __builtin_amdgcn_mfma_f32_16x16x32_bf16(pb1, vh1, a, 0, 0, 0);
            o_[db] = a;
        }
    }

    // ---- epilogue: normalize, split, write A2 [Ah|Al] ----
    const int mrow = (b << 10) + i0 + 16 * w + l4 * 4;
#pragma unroll
    for (int r = 0; r < 4; ++r) {
        const float inv = 1.f / l_[r];
        ushort_t* rowp = A2 + (size_t)(mrow + r) * 1536;
#pragma unroll
        for (int db = 0; db < 4; ++db) {
            const float val = o_[db][r] * inv;
            const ushort_t hi = f2b(val);
            const ushort_t lo = f2b(val - b2f(hi));
            const int c = (h << 6) + 16 * db + lm;
            rowp[c] = hi;
            rowp[768 + c] = lo;
        }
    }
}

extern "C" void kernel_launch(void* const* d_in, const int* in_sizes, int n_in,
                              void* d_out, int out_size, void* d_ws, size_t ws_size,
                              hipStream_t stream) {
    const float* x   = (const float*)d_in[0];
    const float* pos = (const float*)d_in[1];
    const float* Wq  = (const float*)d_in[2];
    const float* bq  = (const float*)d_in[3];
    const float* Wk  = (const float*)d_in[4];
    const float* bk  = (const float*)d_in[5];
    const float* Wv  = (const float*)d_in[6];
    const float* bv  = (const float*)d_in[7];
    const float* Wo  = (const float*)d_in[8];
    const float* bo  = (const float*)d_in[9];
    const float* W1  = (const float*)d_in[10];
    const float* b1  = (const float*)d_in[11];
    const float* W2  = (const float*)d_in[12];
    const float* b2  = (const float*)d_in[13];
    float* out = (float*)d_out;

    // ws: 6 split planes (6 x 6.29MB) | A2 12.6MB | W2b 7.1MB | BiasH 100.7MB
    ushort_t* Qhb = (ushort_t*)d_ws;          // [48][1024][64]
    ushort_t* Qlb = Qhb + 3145728;
    ushort_t* Khb = Qlb + 3145728;
    ushort_t* Klb = Khb + 3145728;
    ushort_t* Vth = Klb + 3145728;            // [48][64][1024]
    ushort_t* Vtl = Vth + 3145728;
    ushort_t* A2  = Vtl + 3145728;            // [4096][1536]
    ushort_t* W2b = A2 + 6291456;             // [2304][1536]
    __half* BiasH = (__half*)(W2b + 3538944); // [48][1024][1024]

    split_hi_lo<<<3072, 256, 0, stream>>>(x, A2);
    split_wT<<<dim3(12, 12), 256, 0, stream>>>(Wq, W2b, 0);
    split_wT<<<dim3(12, 12), 256, 0, stream>>>(Wk, W2b, 768);
    split_wT<<<dim3(12, 12), 256, 0, stream>>>(Wv, W2b, 1536);

    mfma_gemm<1><<<dim3(18, 32), 256, 0, stream>>>(
        A2, W2b, bq, bk, bv, Qhb, Qlb, Khb, Klb, Vth, Vtl, nullptr);

    bias_mlp<<<dim3(1024, 4, 2), 256, 0, stream>>>(pos, W1, b1, W2, b2, BiasH);

    attn_mfma<<<768, 256, 0, stream>>>(Qhb, Qlb, Khb, Klb, Vth, Vtl, BiasH, A2);

    split_wT<<<dim3(12, 12), 256, 0, stream>>>(Wo, W2b, 0);
    mfma_gemm<0><<<dim3(6, 32), 256, 0, stream>>>(
        A2, W2b, bo, nullptr, nullptr, nullptr, nullptr, nullptr, nullptr, nullptr,
        nullptr, out);
}

// Round 9
// 318.602 us; speedup vs baseline: 1.2360x; 1.0516x over previous
//
#include <hip/hip_runtime.h>
#include <hip/hip_fp16.h>

// SpatialAwareAttention — round 9.
//  - attn v3: rows-32/wave (128-thr blocks), fixed-base softmax (bias tensor
//    carries a -12 shift; exp overflow-safe by input bounds), deferred-l,
//    u32-packed P with v_perm unpack. DS ops/wave-tile 100 -> ~72 while MFMA
//    doubles to 96.
//  - bias_mlp v2: weights via wave-uniform (SGPR) loads, W2 pre-transposed.
//  - bf16x3 co-staged GEMMs unchanged from round 8.

typedef unsigned short ushort_t;
typedef unsigned int uint_t;
typedef __attribute__((ext_vector_type(8))) short bf16x8;
typedef __attribute__((ext_vector_type(4))) float f32x4;

__device__ __forceinline__ ushort_t f2b(float f) {  // fp32 -> bf16 (RNE)
    union { float f; uint_t u; } v;
    v.f = f;
    uint_t r = v.u + 0x7fffu + ((v.u >> 16) & 1u);
    return (ushort_t)(r >> 16);
}
__device__ __forceinline__ float b2f(ushort_t b) {
    union { uint_t u; float f; } v;
    v.u = ((uint_t)b) << 16;
    return v.f;
}

__device__ __forceinline__ void gload16(const void* g, void* l) {
    __builtin_amdgcn_global_load_lds(
        (const __attribute__((address_space(1))) unsigned int*)g,
        (__attribute__((address_space(3))) unsigned int*)l, 16, 0, 0);
}

// ---------------------------------------------------------------------------
// X[4096][768] fp32 -> X2[4096][1536] bf16 as [hi | lo]
// ---------------------------------------------------------------------------
__global__ __launch_bounds__(256) void split_hi_lo(const float* __restrict__ X,
                                                   ushort_t* __restrict__ X2) {
    const int idx = blockIdx.x * 256 + threadIdx.x;
    const int m = idx / 192, k4 = (idx - m * 192) * 4;
    float4 v = *(const float4*)&X[(size_t)m * 768 + k4];
    ushort4 hi, lo;
    hi.x = f2b(v.x); lo.x = f2b(v.x - b2f(hi.x));
    hi.y = f2b(v.y); lo.y = f2b(v.y - b2f(hi.y));
    hi.z = f2b(v.z); lo.z = f2b(v.z - b2f(hi.z));
    hi.w = f2b(v.w); lo.w = f2b(v.w - b2f(hi.w));
    ushort_t* row = X2 + (size_t)m * 1536;
    *(ushort4*)&row[k4]       = hi;
    *(ushort4*)&row[768 + k4] = lo;
}

// ---------------------------------------------------------------------------
// W[768 k][768 n] fp32 -> Wt[n_base+n][1536] bf16 as [hi | lo] along k
// ---------------------------------------------------------------------------
__global__ __launch_bounds__(256) void split_wT(const float* __restrict__ W,
                                                ushort_t* __restrict__ Wt,
                                                int n_base) {
    __shared__ float Ws[64][65];
    const int t = threadIdx.x;
    const int rr0 = blockIdx.x * 64, nn0 = blockIdx.y * 64;
    const int c = t & 63, r4 = t >> 6;
#pragma unroll
    for (int e = 0; e < 16; ++e) {
        const int r = r4 + e * 4;
        Ws[r][c] = W[(size_t)(rr0 + r) * 768 + nn0 + c];
    }
    __syncthreads();
#pragma unroll
    for (int e = 0; e < 16; ++e) {
        const int nloc = r4 + e * 4;
        const float v = Ws[c][nloc];
        const ushort_t h = f2b(v);
        const ushort_t l = f2b(v - b2f(h));
        ushort_t* rowp = Wt + (size_t)(n_base + nn0 + nloc) * 1536 + rr0 + c;
        rowp[0]   = h;
        rowp[768] = l;
    }
}

// ---------------------------------------------------------------------------
// W2[32][12] -> W2t[12][32] fp32 (for SGPR-friendly bias_mlp reads)
// ---------------------------------------------------------------------------
__global__ __launch_bounds__(384) void prep_w2t(const float* __restrict__ W2,
                                                float* __restrict__ W2t) {
    const int t = threadIdx.x;  // 384 = 12*32
    const int h = t >> 5, u = t & 31;
    W2t[t] = W2[u * 12 + h];
}

// ---------------------------------------------------------------------------
// GEMM: C[4096 x N] = A @ W  (bf16x3: AhWh + AhWl + AlWh).
// 128x128 tile, BK=32, 4 co-staged planes {Ah,Al,Wh,Wl} = 32KB single-buffer,
// 24 steps x 48 MFMA/wave. XCD-chunked block swizzle.  (unchanged, round 8)
// ---------------------------------------------------------------------------
template <int QKV>
__global__ __launch_bounds__(256) void mfma_gemm(
    const ushort_t* __restrict__ A2, const ushort_t* __restrict__ Bt,
    const float* __restrict__ bv0, const float* __restrict__ bv1,
    const float* __restrict__ bv2, ushort_t* __restrict__ Qh,
    ushort_t* __restrict__ Ql, ushort_t* __restrict__ Kh,
    ushort_t* __restrict__ Kl, ushort_t* __restrict__ Vth,
    ushort_t* __restrict__ Vtl, float* __restrict__ C0) {
    __shared__ ushort_t Ls[4][128 * 32];   // 0=Ah 1=Al 2=Wh 3=Wl

    const int t = threadIdx.x;
    const int w = t >> 6, lane = t & 63;
    const int lm = lane & 15, l4 = lane >> 4;

    const int nbx = QKV ? 18 : 6;
    const int lid0 = blockIdx.y * nbx + blockIdx.x;
    const int cpx = (nbx * 32) >> 3;
    const int lid = (lid0 & 7) * cpx + (lid0 >> 3);
    const int n0 = (lid % nbx) * 128;
    const int m0 = (lid / nbx) * 128;

    const int wr = (w >> 1) * 64, wc = (w & 1) * 64;

    f32x4 acc[4][4];
#pragma unroll
    for (int i = 0; i < 4; ++i)
#pragma unroll
        for (int j = 0; j < 4; ++j) acc[i][j] = (f32x4){0.f, 0.f, 0.f, 0.f};

    const int sr0 = t >> 2, ss0 = t & 3;
    const int sr1 = (t + 256) >> 2, ss1 = (t + 256) & 3;
    const int k80 = (ss0 ^ ((sr0 >> 1) & 3)) << 3;
    const int k81 = (ss1 ^ ((sr1 >> 1) & 3)) << 3;

    const ushort_t* baseA = A2 + (size_t)m0 * 1536;
    const ushort_t* baseB = Bt + (size_t)n0 * 1536;

    for (int q = 0; q < 24; ++q) {
        const int k0 = q * 32;
        __syncthreads();
        {
            gload16(baseA + (size_t)sr0 * 1536 + k0 + k80, (char*)&Ls[0][0] + t * 16);
            gload16(baseA + (size_t)sr1 * 1536 + k0 + k81,
                    (char*)&Ls[0][0] + (t + 256) * 16);
            gload16(baseA + (size_t)sr0 * 1536 + 768 + k0 + k80,
                    (char*)&Ls[1][0] + t * 16);
            gload16(baseA + (size_t)sr1 * 1536 + 768 + k0 + k81,
                    (char*)&Ls[1][0] + (t + 256) * 16);
            gload16(baseB + (size_t)sr0 * 1536 + k0 + k80, (char*)&Ls[2][0] + t * 16);
            gload16(baseB + (size_t)sr1 * 1536 + k0 + k81,
                    (char*)&Ls[2][0] + (t + 256) * 16);
            gload16(baseB + (size_t)sr0 * 1536 + 768 + k0 + k80,
                    (char*)&Ls[3][0] + t * 16);
            gload16(baseB + (size_t)sr1 * 1536 + 768 + k0 + k81,
                    (char*)&Ls[3][0] + (t + 256) * 16);
        }
        __syncthreads();

        bf16x8 ah[4], al[4];
#pragma unroll
        for (int i = 0; i < 4; ++i) {
            const int ra = wr + i * 16 + lm;
            const int sa = (l4 ^ ((ra >> 1) & 3)) << 4;
            ah[i] = *(const bf16x8*)((const char*)&Ls[0][0] + ra * 64 + sa);
            al[i] = *(const bf16x8*)((const char*)&Ls[1][0] + ra * 64 + sa);
        }
#pragma unroll
        for (int j = 0; j < 4; ++j) {
            const int rb = wc + j * 16 + lm;
            const int sb = (l4 ^ ((rb >> 1) & 3)) << 4;
            const bf16x8 bh = *(const bf16x8*)((const char*)&Ls[2][0] + rb * 64 + sb);
            const bf16x8 bl = *(const bf16x8*)((const char*)&Ls[3][0] + rb * 64 + sb);
#pragma unroll
            for (int i = 0; i < 4; ++i) {
                acc[i][j] = __builtin_amdgcn_mfma_f32_16x16x32_bf16(ah[i], bh,
                                                                    acc[i][j], 0, 0, 0);
                acc[i][j] = __builtin_amdgcn_mfma_f32_16x16x32_bf16(ah[i], bl,
                                                                    acc[i][j], 0, 0, 0);
                acc[i][j] = __builtin_amdgcn_mfma_f32_16x16x32_bf16(al[i], bh,
                                                                    acc[i][j], 0, 0, 0);
            }
        }
    }

    const int cl = lane & 15, rg = (lane >> 4) * 4;
    if constexpr (QKV) {
        const int which = n0 / 768;
        const int nb = n0 - which * 768 + wc;
        const float* bb = which == 0 ? bv0 : (which == 1 ? bv1 : bv2);
#pragma unroll
        for (int i = 0; i < 4; ++i)
#pragma unroll
            for (int j = 0; j < 4; ++j) {
                const int cw = nb + j * 16 + cl;
                const int h = cw >> 6, d = cw & 63;
                const float badd = bb[cw];
#pragma unroll
                for (int r = 0; r < 4; ++r) {
                    const int gr = m0 + wr + i * 16 + rg + r;
                    const int b = gr >> 10, l = gr & 1023;
                    const int bh2 = b * 12 + h;
                    float val = acc[i][j][r] + badd;
                    if (which == 0) val *= 0.125f;
                    const ushort_t hi = f2b(val);
                    const ushort_t lo = f2b(val - b2f(hi));
                    if (which == 0) {
                        const size_t idx = ((size_t)((bh2 << 10) + l)) * 64 + d;
                        Qh[idx] = hi; Ql[idx] = lo;
                    } else if (which == 1) {
                        const size_t idx = ((size_t)((bh2 << 10) + l)) * 64 + d;
                        Kh[idx] = hi; Kl[idx] = lo;
                    } else {
                        const size_t idx = (((size_t)((bh2 << 6) + d)) << 10) + l;
                        Vth[idx] = hi; Vtl[idx] = lo;
                    }
                }
            }
    } else {
#pragma unroll
        for (int i = 0; i < 4; ++i)
#pragma unroll
            for (int j = 0; j < 4; ++j) {
                const int gc = n0 + wc + j * 16 + cl;
#pragma unroll
                for (int r = 0; r < 4; ++r) {
                    const int gr = m0 + wr + i * 16 + rg + r;
                    C0[(size_t)gr * 768 + gc] = acc[i][j][r] + bv0[gc];
                }
            }
    }
}

// ---------------------------------------------------------------------------
// bias[b][h][i][j] = relu(delta@W1+b1)@W2[:,h] + b2[h] - 12  -> fp16
// (the -12 is the fixed softmax base; softmax is shift-invariant).
// Weights read via wave-uniform loads -> SGPR broadcast; no LDS.
// Grid (1024 i, 4 b, 2 jz); thread: j = jz*512 + {2t, 2t+1}.
// ---------------------------------------------------------------------------
__global__ __launch_bounds__(256) void bias_mlp(const float* __restrict__ pos,
                                                const float* __restrict__ W1,
                                                const float* __restrict__ b1,
                                                const float* __restrict__ W2t,
                                                const float* __restrict__ b2,
                                                __half* __restrict__ Bias) {
    const int t = threadIdx.x;
    const int i = blockIdx.x;
    const int b = blockIdx.y;
    const int j0 = blockIdx.z * 512;

    const float2 pi2 = *(const float2*)&pos[((b << 10) + i) << 1];
    const float4 pj01 = *(const float4*)&pos[((b << 10) + j0 + 2 * t) << 1];
    float dx[2], dy[2];
    dx[0] = pi2.x - pj01.x; dy[0] = pi2.y - pj01.y;
    dx[1] = pi2.x - pj01.z; dy[1] = pi2.y - pj01.w;

    float acc[2][12];
#pragma unroll
    for (int h = 0; h < 12; ++h) {
        const float bb = b2[h] - 12.f;
        acc[0][h] = bb;
        acc[1][h] = bb;
    }

    for (int u4 = 0; u4 < 8; ++u4) {   // runtime loop -> bounded SGPR pressure
        const float4 ax = *(const float4*)&W1[u4 * 4];        // uniform -> s_load
        const float4 ay = *(const float4*)&W1[32 + u4 * 4];
        const float4 ab = *(const float4*)&b1[u4 * 4];
        float4 hv[2];
#pragma unroll
        for (int e = 0; e < 2; ++e) {
            hv[e].x = fmaxf(fmaf(dx[e], ax.x, fmaf(dy[e], ay.x, ab.x)), 0.f);
            hv[e].y = fmaxf(fmaf(dx[e], ax.y, fmaf(dy[e], ay.y, ab.y)), 0.f);
            hv[e].z = fmaxf(fmaf(dx[e], ax.z, fmaf(dy[e], ay.z, ab.z)), 0.f);
            hv[e].w = fmaxf(fmaf(dx[e], ax.w, fmaf(dy[e], ay.w, ab.w)), 0.f);
        }
#pragma unroll
        for (int h = 0; h < 12; ++h) {
            const float4 wv = *(const float4*)&W2t[h * 32 + u4 * 4];  // uniform
#pragma unroll
            for (int e = 0; e < 2; ++e)
                acc[e][h] = fmaf(hv[e].x, wv.x,
                            fmaf(hv[e].y, wv.y,
                            fmaf(hv[e].z, wv.z,
                            fmaf(hv[e].w, wv.w, acc[e][h]))));
        }
    }

    const size_t base = (((size_t)(b * 12)) << 20) + (((size_t)i) << 10) + j0;
#pragma unroll
    for (int h = 0; h < 12; ++h)
        *(__half2*)&Bias[base + (((size_t)h) << 20) + 2 * t] =
            __floats2half2_rn(acc[0][h], acc[1][h]);
}

// ---------------------------------------------------------------------------
// MFMA flash attention v3. Grid 768 (XCD-swizzled), 128 threads = 2 waves.
// Wave w owns rows [32w, 32w+32) of the 64-row i-tile (2 row-groups of 16).
// Fixed-base softmax (bias carries -12): no max reduce, no rescale; l is a
// pure sum deferred to the epilogue. P packed u32 (bf16 hi|lo), v_perm unpack.
// LDS 48KB -> 3 blocks/CU.
// ---------------------------------------------------------------------------
__global__ __launch_bounds__(128) void attn_mfma(
    const ushort_t* __restrict__ Qh, const ushort_t* __restrict__ Ql,
    const ushort_t* __restrict__ Kh, const ushort_t* __restrict__ Kl,
    const ushort_t* __restrict__ Vth, const ushort_t* __restrict__ Vtl,
    const __half* __restrict__ BiasT, ushort_t* __restrict__ A2) {
    __shared__ ushort_t Kls[2][64][64];                       // 16KB
    __shared__ ushort_t Vls[2][64][64];                       // 16KB
    __shared__ __align__(16) uint_t P32[2][2][16][64];        // 16KB

    const int t = threadIdx.x;
    const int wgid0 = blockIdx.x;
    const int wgid = (wgid0 & 7) * 96 + (wgid0 >> 3);  // XCD chunk swizzle
    const int bh = wgid >> 4, it = wgid & 15;
    const int b = bh / 12, h = bh - b * 12;
    const int i0 = it << 6;
    const int w = t >> 6, l = t & 63;
    const int l4 = l >> 4, lm = l & 15;
    const int rowbase = i0 + 32 * w;

    const __half* bpb = BiasT + (((size_t)bh) << 20) +
                        (((size_t)(rowbase + l4 * 4)) << 10) + lm;

    // Q fragments for both row-groups (held in registers)
    bf16x8 qh_[2][2], ql_[2][2];
#pragma unroll
    for (int rg = 0; rg < 2; ++rg) {
        const size_t qoff =
            ((size_t)((bh << 10) + rowbase + rg * 16 + lm)) * 64 + l4 * 8;
        qh_[rg][0] = *(const bf16x8*)(Qh + qoff);
        qh_[rg][1] = *(const bf16x8*)(Qh + qoff + 32);
        ql_[rg][0] = *(const bf16x8*)(Ql + qoff);
        ql_[rg][1] = *(const bf16x8*)(Ql + qoff + 32);
    }

    float lsum[2][4];
    f32x4 o_[2][4];
#pragma unroll
    for (int rg = 0; rg < 2; ++rg)
#pragma unroll
        for (int r = 0; r < 4; ++r) {
            lsum[rg][r] = 0.f;
            o_[rg][r] = (f32x4){0.f, 0.f, 0.f, 0.f};
        }

    for (int jt = 0; jt < 16; ++jt) {
        const int j0 = jt << 6;

        float bias_r[2][4][4];
#pragma unroll
        for (int rg = 0; rg < 2; ++rg)
#pragma unroll
            for (int cb = 0; cb < 4; ++cb)
#pragma unroll
                for (int r = 0; r < 4; ++r)
                    bias_r[rg][cb][r] = __half2float(
                        bpb[((rg * 16 + r) << 10) + j0 + 16 * cb]);

        __syncthreads();
        {   // wave w stages two 8KB planes: w0 -> Kh,Kl ; w1 -> Vth,Vtl
            const ushort_t* g0 = (w == 0) ? Kh : Vth;
            const ushort_t* g1 = (w == 0) ? Kl : Vtl;
            ushort_t* lb0 = (w == 0) ? &Kls[0][0][0] : &Vls[0][0][0];
            ushort_t* lb1 = (w == 0) ? &Kls[1][0][0] : &Vls[1][0][0];
#pragma unroll
            for (int ch = 0; ch < 8; ++ch) {
                const int row = ch * 8 + (l >> 3);
                const int off8 = (((l & 7) ^ (row & 7)) << 3);
                const ushort_t* s0 =
                    (w == 0) ? g0 + ((size_t)((bh << 10) + j0 + row)) * 64 + off8
                             : g0 + ((size_t)((bh << 6) + row)) * 1024 + j0 + off8;
                const ushort_t* s1 =
                    (w == 0) ? g1 + ((size_t)((bh << 10) + j0 + row)) * 64 + off8
                             : g1 + ((size_t)((bh << 6) + row)) * 1024 + j0 + off8;
                gload16(s0, (char*)lb0 + ch * 1024);
                gload16(s1, (char*)lb1 + ch * 1024);
            }
        }
        __syncthreads();

        // ---- S = Q.K^T (QhKh + QhKl + QlKh), K frags shared by both rg ----
        f32x4 s_[2][4];
#pragma unroll
        for (int cb = 0; cb < 4; ++cb) {
            const int row = 16 * cb + lm;
            const int sw = row & 7;
            const char* k0p = (const char*)&Kls[0][0][0] + row * 128;
            const char* k1p = (const char*)&Kls[1][0][0] + row * 128;
            const bf16x8 kh0 = *(const bf16x8*)(k0p + ((l4 + 0) ^ sw) * 16);
            const bf16x8 kh1 = *(const bf16x8*)(k0p + ((l4 + 4) ^ sw) * 16);
            const bf16x8 kl0 = *(const bf16x8*)(k1p + ((l4 + 0) ^ sw) * 16);
            const bf16x8 kl1 = *(const bf16x8*)(k1p + ((l4 + 4) ^ sw) * 16);
#pragma unroll
            for (int rg = 0; rg < 2; ++rg) {
                f32x4 a = (f32x4){0.f, 0.f, 0.f, 0.f};
                a = __builtin_amdgcn_mfma_f32_16x16x32_bf16(qh_[rg][0], kh0, a, 0, 0, 0);
                a = __builtin_amdgcn_mfma_f32_16x16x32_bf16(qh_[rg][1], kh1, a, 0, 0, 0);
                a = __builtin_amdgcn_mfma_f32_16x16x32_bf16(qh_[rg][0], kl0, a, 0, 0, 0);
                a = __builtin_amdgcn_mfma_f32_16x16x32_bf16(qh_[rg][1], kl1, a, 0, 0, 0);
                a = __builtin_amdgcn_mfma_f32_16x16x32_bf16(ql_[rg][0], kh0, a, 0, 0, 0);
                a = __builtin_amdgcn_mfma_f32_16x16x32_bf16(ql_[rg][1], kh1, a, 0, 0, 0);
                s_[rg][cb] = a;
            }
        }

        // ---- P = exp(S + bias') ; pack bf16 hi|lo into u32, store to LDS ----
#pragma unroll
        for (int rg = 0; rg < 2; ++rg) {
            uint_t* pw = &P32[w][rg][0][0];
#pragma unroll
            for (int cb = 0; cb < 4; ++cb)
#pragma unroll
                for (int r = 0; r < 4; ++r) {
                    const float p = __expf(s_[rg][cb][r] + bias_r[rg][cb][r]);
                    lsum[rg][r] += p;
                    const uint_t pu = __float_as_uint(p);
                    const ushort_t ph = (ushort_t)(pu >> 16);  // trunc hi
                    const float rem = p - __uint_as_float(pu & 0xffff0000u);
                    const ushort_t pl2 = f2b(rem);
                    const uint_t packed = (uint_t)ph | ((uint_t)pl2 << 16);
                    const int rl = l4 * 4 + r;
                    const int col = (16 * cb + lm) ^ (l4 << 4);
                    pw[rl * 64 + col] = packed;
                }
        }

        // ---- unpack P A-fragments (same-wave LDS read + v_perm split) ----
        bf16x8 pah[2][2], pal[2][2];
#pragma unroll
        for (int rg = 0; rg < 2; ++rg) {
            const uint_t* prow = &P32[w][rg][lm][0];
            const int key = ((lm >> 2) & 3) << 4;
#pragma unroll
            for (int ss = 0; ss < 2; ++ss) {
                const int col0 = ((l4 + 4 * ss) * 8) ^ key;
                const uint4 qa = *(const uint4*)&prow[col0];
                const uint4 qb = *(const uint4*)&prow[col0 + 4];
                union { uint_t u[4]; bf16x8 v; } hi, lo;
                hi.u[0] = __builtin_amdgcn_perm(qa.y, qa.x, 0x05040100u);
                hi.u[1] = __builtin_amdgcn_perm(qa.w, qa.z, 0x05040100u);
                hi.u[2] = __builtin_amdgcn_perm(qb.y, qb.x, 0x05040100u);
                hi.u[3] = __builtin_amdgcn_perm(qb.w, qb.z, 0x05040100u);
                lo.u[0] = __builtin_amdgcn_perm(qa.y, qa.x, 0x07060302u);
                lo.u[1] = __builtin_amdgcn_perm(qa.w, qa.z, 0x07060302u);
                lo.u[2] = __builtin_amdgcn_perm(qb.y, qb.x, 0x07060302u);
                lo.u[3] = __builtin_amdgcn_perm(qb.w, qb.z, 0x07060302u);
                pah[rg][ss] = hi.v;
                pal[rg][ss] = lo.v;
            }
        }

        // ---- O += P.V (PhVh + PhVl + PlVh), V frags shared by both rg ----
#pragma unroll
        for (int db = 0; db < 4; ++db) {
            const int vrow = 16 * db + lm;
            const int vw = vrow & 7;
            const char* v0p = (const char*)&Vls[0][0][0] + vrow * 128;
            const char* v1p = (const char*)&Vls[1][0][0] + vrow * 128;
            const bf16x8 vh0 = *(const bf16x8*)(v0p + ((l4 + 0) ^ vw) * 16);
            const bf16x8 vh1 = *(const bf16x8*)(v0p + ((l4 + 4) ^ vw) * 16);
            const bf16x8 vl0 = *(const bf16x8*)(v1p + ((l4 + 0) ^ vw) * 16);
            const bf16x8 vl1 = *(const bf16x8*)(v1p + ((l4 + 4) ^ vw) * 16);
#pragma unroll
            for (int rg = 0; rg < 2; ++rg) {
                f32x4 a = o_[rg][db];
                a = __builtin_amdgcn_mfma_f32_16x16x32_bf16(pah[rg][0], vh0, a, 0, 0, 0);
                a = __builtin_amdgcn_mfma_f32_16x16x32_bf16(pah[rg][1], vh1, a, 0, 0, 0);
                a = __builtin_amdgcn_mfma_f32_16x16x32_bf16(pah[rg][0], vl0, a, 0, 0, 0);
                a = __builtin_amdgcn_mfma_f32_16x16x32_bf16(pah[rg][1], vl1, a, 0, 0, 0);
                a = __builtin_amdgcn_mfma_f32_16x16x32_bf16(pal[rg][0], vh0, a, 0, 0, 0);
                a = __builtin_amdgcn_mfma_f32_16x16x32_bf16(pal[rg][1], vh1, a, 0, 0, 0);
                o_[rg][db] = a;
            }
        }
    }

    // ---- epilogue: reduce l over lm lanes, normalize, split, write A2 ----
#pragma unroll
    for (int rg = 0; rg < 2; ++rg)
#pragma unroll
        for (int r = 0; r < 4; ++r) {
            float lf = lsum[rg][r];
            lf += __shfl_xor(lf, 1);
            lf += __shfl_xor(lf, 2);
            lf += __shfl_xor(lf, 4);
            lf += __shfl_xor(lf, 8);
            const float inv = 1.f / lf;
            const int row = (b << 10) + rowbase + rg * 16 + l4 * 4 + r;
            ushort_t* rowp = A2 + (size_t)row * 1536;
#pragma unroll
            for (int db = 0; db < 4; ++db) {
                const float val = o_[rg][db][r] * inv;
                const ushort_t hi = f2b(val);
                const ushort_t lo = f2b(val - b2f(hi));
                const int c = (h << 6) + 16 * db + lm;
                rowp[c] = hi;
                rowp[768 + c] = lo;
            }
        }
}

extern "C" void kernel_launch(void* const* d_in, const int* in_sizes, int n_in,
                              void* d_out, int out_size, void* d_ws, size_t ws_size,
                              hipStream_t stream) {
    const float* x   = (const float*)d_in[0];
    const float* pos = (const float*)d_in[1];
    const float* Wq  = (const float*)d_in[2];
    const float* bq  = (const float*)d_in[3];
    const float* Wk  = (const float*)d_in[4];
    const float* bk  = (const float*)d_in[5];
    const float* Wv  = (const float*)d_in[6];
    const float* bv  = (const float*)d_in[7];
    const float* Wo  = (const float*)d_in[8];
    const float* bo  = (const float*)d_in[9];
    const float* W1  = (const float*)d_in[10];
    const float* b1  = (const float*)d_in[11];
    const float* W2  = (const float*)d_in[12];
    const float* b2  = (const float*)d_in[13];
    float* out = (float*)d_out;

    ushort_t* Qhb = (ushort_t*)d_ws;          // [48][1024][64]
    ushort_t* Qlb = Qhb + 3145728;
    ushort_t* Khb = Qlb + 3145728;
    ushort_t* Klb = Khb + 3145728;
    ushort_t* Vth = Klb + 3145728;            // [48][64][1024]
    ushort_t* Vtl = Vth + 3145728;
    ushort_t* A2  = Vtl + 3145728;            // [4096][1536]
    ushort_t* W2b = A2 + 6291456;             // [2304][1536]
    __half* BiasH = (__half*)(W2b + 3538944); // [48][1024][1024]
    float* W2t    = (float*)(BiasH + 50331648); // [12][32]

    split_hi_lo<<<3072, 256, 0, stream>>>(x, A2);
    split_wT<<<dim3(12, 12), 256, 0, stream>>>(Wq, W2b, 0);
    split_wT<<<dim3(12, 12), 256, 0, stream>>>(Wk, W2b, 768);
    split_wT<<<dim3(12, 12), 256, 0, stream>>>(Wv, W2b, 1536);
    prep_w2t<<<1, 384, 0, stream>>>(W2, W2t);

    mfma_gemm<1><<<dim3(18, 32), 256, 0, stream>>>(
        A2, W2b, bq, bk, bv, Qhb, Qlb, Khb, Klb, Vth, Vtl, nullptr);

    bias_mlp<<<dim3(1024, 4, 2), 256, 0, stream>>>(pos, W1, b1, W2t, b2, BiasH);

    attn_mfma<<<768, 128, 0, stream>>>(Qhb, Qlb, Khb, Klb, Vth, Vtl, BiasH, A2);

    split_wT<<<dim3(12, 12), 256, 0, stream>>>(Wo, W2b, 0);
    mfma_gemm<0><<<dim3(6, 32), 256, 0, stream>>>(
        A2, W2b, bo, nullptr, nullptr, nullptr, nullptr, nullptr, nullptr, nullptr,
        nullptr, out);
}